// Round 2
// 15131.039 us; speedup vs baseline: 1.8314x; 1.8314x over previous
//
#include <hip/hip_runtime.h>
#include <hip/hip_cooperative_groups.h>
#include <cmath>

namespace cg = cooperative_groups;

// Problem constants
constexpr int B_ = 128, T_ = 512, N_ = 512;
// Partition: 8 batch-groups x 32 N-slices = 256 WGs (1 per CU), 256 threads each.
// gb = w & 7 -> with round-robin WG->XCD dispatch the 32 WGs of a batch group
// land on ONE XCD, so the group barrier and all intra-group producer/consumer
// traffic (AC, Fp, h-history) stay XCD-local. Correctness does NOT depend on
// the mapping (agent-scope release/acquire handles cross-XCD visibility);
// only locality does. Groups are data-independent and free-run.
constexpr int GB = 8, GN = 32, BS = 16, NS = 16;
constexpr int WGS = GB * GN, THREADS = 256;

// LDS layout (floats). Row stride 608 + skew swizzle keeps (bq,kc) lane
// patterns at <=2-way bank aliasing (free, m136).
constexpr int STRIDE = 608;
constexpr int OFF_WI  = 0;                       // Wi[:,1:] slice, 16 rows
constexpr int OFF_WH  = OFF_WI + NS * STRIDE;    // Wh[:,1:] slice
constexpr int OFF_C   = OFF_WH + NS * STRIDE;    // c_{t-1} tile, 16 batches x 512
constexpr int OFF_RED = OFF_C + BS * STRIDE;     // sRed[4 waves][16 tiles][17]
constexpr int OFF_HN  = OFF_RED + 4 * 16 * 17;   // h_new tile [16][17]
constexpr int OFF_PART= OFF_HN + 16 * 17;        // f partial reduce [16][17]
constexpr int OFF_F   = OFF_PART + 16 * 17;      // f_{t-1}[16]
constexpr int OFF_XT  = OFF_F + 16;              // x_t[16]
constexpr int OFF_WF  = OFF_XT + 16;             // Wf[1+j] slice
constexpr int OFF_XW  = OFF_WF + 16;             // Wi[j][0]+Wh[j][0]
constexpr int OFF_GC  = OFF_XW + 16;             // bi[j]+bh[j]
constexpr int SMEM_FLOATS = OFF_GC + 16;         // 30896 floats = 123.6 KB

__device__ __forceinline__ int swz(int r, int k) {
  return r * STRIDE + k + ((k >> 5) << 2) + (((r >> 2) & 3) << 3);
}

// 32-WG monotonic barrier, one counter (own 256B line) per batch group.
// __syncthreads() before arrival drains this WG's global stores (vmcnt) to L2;
// the RELEASE fetch_add performs the L2 writeback for agent scope; the ACQUIRE
// load on exit invalidates stale L1/L2 so post-barrier reads observe
// group-mates' writes. Counter is monotonic (no reuse/ABA); target = t*32.
__device__ __forceinline__ void group_barrier(unsigned* bar, int gb, unsigned target) {
  __syncthreads();
  if (threadIdx.x == 0) {
    unsigned* ctr = bar + gb * 64;   // 256B spacing: no false sharing
    __hip_atomic_fetch_add(ctr, 1u, __ATOMIC_RELEASE, __HIP_MEMORY_SCOPE_AGENT);
    // relaxed spin (no per-poll cache maintenance), short sleep backoff
    while (__hip_atomic_load(ctr, __ATOMIC_RELAXED, __HIP_MEMORY_SCOPE_AGENT) < target) {
      __builtin_amdgcn_s_sleep(1);
    }
    (void)__hip_atomic_load(ctr, __ATOMIC_ACQUIRE, __HIP_MEMORY_SCOPE_AGENT);
  }
  __syncthreads();
}

__global__ void hippo_kernel(const float* __restrict__ x,  const float* __restrict__ h0,
                             const float* __restrict__ c0, const float* __restrict__ Wi,
                             const float* __restrict__ bi, const float* __restrict__ Wh,
                             const float* __restrict__ bh, const float* __restrict__ Wf,
                             const float* __restrict__ bfp,const float* __restrict__ Ast,
                             const float* __restrict__ Bst,
                             float* __restrict__ out, float* __restrict__ AC,
                             float* __restrict__ Fp, unsigned* __restrict__ bar)
{
  extern __shared__ __align__(16) float lds[];
  cg::grid_group grid = cg::this_grid();
  const int tid = threadIdx.x;
  const int w   = blockIdx.x;
  const int gb  = w & 7;    // batch-group id (== XCD id under round-robin dispatch)
  const int gn  = w >> 3;   // N-slice id within the group
  const int j0  = gn * NS;
  const int b0  = gb * BS;

  // ---- barrier counters: self-init (no hipMemsetAsync in graph capture).
  // WG 0 zeroes all 8 counters; ONE grid.sync() per launch makes the zeros
  // visible before any group barrier is used. ----
  if (w == 0 && tid < GB)
    __hip_atomic_store(bar + tid * 64, 0u, __ATOMIC_RELEASE, __HIP_MEMORY_SCOPE_AGENT);

  // ---- one-time init: weight slices + per-j constants into LDS ----
  for (int idx = tid; idx < NS * 512; idx += THREADS) {
    int jj = idx >> 9, k = idx & 511;
    lds[OFF_WI + swz(jj, k)] = Wi[(j0 + jj) * 513 + 1 + k];
    lds[OFF_WH + swz(jj, k)] = Wh[(j0 + jj) * 513 + 1 + k];
  }
  if (tid < 16) {
    lds[OFF_WF + tid] = Wf[1 + j0 + tid];
    lds[OFF_XW + tid] = Wi[(j0 + tid) * 513] + Wh[(j0 + tid) * 513];
    lds[OFF_GC + tid] = bi[j0 + tid] + bh[j0 + tid];
  }
  const float wf0 = Wf[0];
  const float bf0 = bfp[0];

  grid.sync();   // once per launch: barrier counters zeroed + LDS init done

  const int jq   = tid & 3;          // j (or i) quad
  const int bq   = (tid >> 2) & 3;   // b quad
  const int kc   = tid >> 4;         // k chunk of 32 (16 chunks)
  const int wave = tid >> 6;

  for (int t = 1; t <= T_; ++t) {
    const int bufp = (t - 1) & 1;
    const int bufc = t & 1;

    // ---- A1: gather f partials (written by all 32 slice-WGs last step) + x_t ----
    {
      int g2 = tid >> 4, bb = tid & 15;
      float v = 0.f;
      if (t > 1) {
        const float* fp = Fp + bufp * GN * B_;
        v = fp[(2 * g2) * B_ + b0 + bb] + fp[(2 * g2 + 1) * B_ + b0 + bb];
      }
      lds[OFF_PART + g2 * 17 + bb] = v;
      if (tid >= 224 && tid < 240) {
        int b2 = tid - 224;
        lds[OFF_XT + b2] = x[(b0 + b2) * T_ + (t - 1)];
      }
    }
    __syncthreads();

    // ---- A2: finalize f_{t-1} per batch ----
    if (tid < 16) {
      float f = 0.f;
      if (t > 1) {
        f = bf0 + wf0 * x[(b0 + tid) * T_ + (t - 2)];
        #pragma unroll
        for (int g2 = 0; g2 < 16; ++g2) f += lds[OFF_PART + g2 * 17 + tid];
      }
      lds[OFF_F + tid] = f;
    }
    __syncthreads();

    // ---- A3: stage c_{t-1} = AC + f*B  (t==1: c0) into LDS ----
    #pragma unroll
    for (int it = 0; it < 8; ++it) {
      int idx = tid + it * THREADS;          // 0..2047
      int bb = idx >> 7, k = (idx & 127) << 2;
      float4 v;
      if (t == 1) {
        v = *reinterpret_cast<const float4*>(c0 + (b0 + bb) * N_ + k);
      } else {
        float4 ac = *reinterpret_cast<const float4*>(AC + bufp * B_ * N_ + (b0 + bb) * N_ + k);
        float4 b4 = *reinterpret_cast<const float4*>(Bst + (t - 2) * N_ + k);
        float f = lds[OFF_F + bb];
        v.x = ac.x + f * b4.x; v.y = ac.y + f * b4.y;
        v.z = ac.z + f * b4.z; v.w = ac.w + f * b4.w;
      }
      *reinterpret_cast<float4*>(&lds[OFF_C + swz(bb, k)]) = v;
    }
    __syncthreads();

    // ---- B: gates = c@Wi' + h@Wh'  (4x4 tile per thread, 16-way k-split) ----
    float acc[4][4];
    #pragma unroll
    for (int a = 0; a < 4; ++a)
      #pragma unroll
      for (int c = 0; c < 4; ++c) acc[a][c] = 0.f;

    const float* hbase = (t == 1) ? (h0 + (long)b0 * N_)
                                  : (out + (long)b0 * T_ * N_ + (long)(t - 2) * N_);
    const long hstride = (t == 1) ? (long)N_ : (long)T_ * N_;

    #pragma unroll 4
    for (int q8 = 0; q8 < 8; ++q8) {
      int k = kc * 32 + q8 * 4;
      float4 c4[4], h4[4], wi4[4], wh4[4];
      #pragma unroll
      for (int bi_ = 0; bi_ < 4; ++bi_) {
        int b = bq * 4 + bi_;
        c4[bi_] = *reinterpret_cast<const float4*>(&lds[OFF_C + swz(b, k)]);
        h4[bi_] = *reinterpret_cast<const float4*>(hbase + b * hstride + k);
      }
      #pragma unroll
      for (int ji = 0; ji < 4; ++ji) {
        int j = jq * 4 + ji;
        wi4[ji] = *reinterpret_cast<const float4*>(&lds[OFF_WI + swz(j, k)]);
        wh4[ji] = *reinterpret_cast<const float4*>(&lds[OFF_WH + swz(j, k)]);
      }
      #pragma unroll
      for (int bi_ = 0; bi_ < 4; ++bi_)
        #pragma unroll
        for (int ji = 0; ji < 4; ++ji) {
          acc[bi_][ji] += c4[bi_].x * wi4[ji].x + c4[bi_].y * wi4[ji].y
                        + c4[bi_].z * wi4[ji].z + c4[bi_].w * wi4[ji].w
                        + h4[bi_].x * wh4[ji].x + h4[bi_].y * wh4[ji].y
                        + h4[bi_].z * wh4[ji].z + h4[bi_].w * wh4[ji].w;
        }
    }
    // in-wave reduce over kc (lane bits 4,5), then cross-wave via LDS
    #pragma unroll
    for (int a = 0; a < 4; ++a)
      #pragma unroll
      for (int c = 0; c < 4; ++c) {
        acc[a][c] += __shfl_xor(acc[a][c], 16, 64);
        acc[a][c] += __shfl_xor(acc[a][c], 32, 64);
      }
    if ((tid & 48) == 0) {
      int tile = tid & 15;
      #pragma unroll
      for (int a = 0; a < 4; ++a)
        #pragma unroll
        for (int c = 0; c < 4; ++c)
          lds[OFF_RED + wave * 272 + tile * 17 + a * 4 + c] = acc[a][c];
    }
    __syncthreads();

    // final gate -> o -> h_new -> store (d_out IS the h history)
    {
      int b = tid >> 4, j = tid & 15;
      int tile = ((b >> 2) << 2) | (j >> 2);
      int a    = ((b & 3) << 2) | (j & 3);
      float g = lds[OFF_RED + 0 * 272 + tile * 17 + a]
              + lds[OFF_RED + 1 * 272 + tile * 17 + a]
              + lds[OFF_RED + 2 * 272 + tile * 17 + a]
              + lds[OFF_RED + 3 * 272 + tile * 17 + a];
      g += lds[OFF_XT + b] * lds[OFF_XW + j] + lds[OFF_GC + j];
      float o  = 1.f / (1.f + expf(-g));
      float cp = lds[OFF_C + swz(b, j0 + j)];
      float hn = o * tanhf(cp);
      out[(long)(b0 + b) * T_ * N_ + (long)(t - 1) * N_ + j0 + j] = hn;
      lds[OFF_HN + b * 17 + j] = hn;
    }
    __syncthreads();
    if (tid < 16) {  // f partial for this slice (consumed next step)
      float p = 0.f;
      #pragma unroll
      for (int jj = 0; jj < 16; ++jj) p += lds[OFF_WF + jj] * lds[OFF_HN + tid * 17 + jj];
      Fp[bufc * GN * B_ + gn * B_ + b0 + tid] = p;
    }

    // ---- C: AC_t = A_t[slice,:] @ c_{t-1} ----
    float acc2[4][4];
    #pragma unroll
    for (int a = 0; a < 4; ++a)
      #pragma unroll
      for (int c = 0; c < 4; ++c) acc2[a][c] = 0.f;
    const float* Arow = Ast + (long)(t - 1) * N_ * N_;
    #pragma unroll 4
    for (int q8 = 0; q8 < 8; ++q8) {
      int k = kc * 32 + q8 * 4;
      float4 a4[4], c4[4];
      #pragma unroll
      for (int ii = 0; ii < 4; ++ii) {
        int i = jq * 4 + ii;
        a4[ii] = *reinterpret_cast<const float4*>(Arow + (long)(j0 + i) * N_ + k);
      }
      #pragma unroll
      for (int bi_ = 0; bi_ < 4; ++bi_) {
        int b = bq * 4 + bi_;
        c4[bi_] = *reinterpret_cast<const float4*>(&lds[OFF_C + swz(b, k)]);
      }
      #pragma unroll
      for (int bi_ = 0; bi_ < 4; ++bi_)
        #pragma unroll
        for (int ii = 0; ii < 4; ++ii)
          acc2[bi_][ii] += c4[bi_].x * a4[ii].x + c4[bi_].y * a4[ii].y
                         + c4[bi_].z * a4[ii].z + c4[bi_].w * a4[ii].w;
    }
    #pragma unroll
    for (int a = 0; a < 4; ++a)
      #pragma unroll
      for (int c = 0; c < 4; ++c) {
        acc2[a][c] += __shfl_xor(acc2[a][c], 16, 64);
        acc2[a][c] += __shfl_xor(acc2[a][c], 32, 64);
      }
    if ((tid & 48) == 0) {
      int tile = tid & 15;
      #pragma unroll
      for (int a = 0; a < 4; ++a)
        #pragma unroll
        for (int c = 0; c < 4; ++c)
          lds[OFF_RED + wave * 272 + tile * 17 + a * 4 + c] = acc2[a][c];
    }
    __syncthreads();
    {
      int b = tid >> 4, i = tid & 15;
      int tile = ((b >> 2) << 2) | (i >> 2);
      int a    = ((b & 3) << 2) | (i & 3);
      float v = lds[OFF_RED + 0 * 272 + tile * 17 + a]
              + lds[OFF_RED + 1 * 272 + tile * 17 + a]
              + lds[OFF_RED + 2 * 272 + tile * 17 + a]
              + lds[OFF_RED + 3 * 272 + tile * 17 + a];
      AC[bufc * B_ * N_ + (b0 + b) * N_ + j0 + i] = v;
    }

    // ONE group barrier per step (32 WGs, XCD-local) — replaces grid.sync()
    group_barrier(bar, gb, (unsigned)t * 32u);
  }

  // ---- epilogue: c_f = AC_T + f_T * B_T ----
  {
    const int bufT = T_ & 1;  // 0
    int g2 = tid >> 4, bb = tid & 15;
    const float* fp = Fp + bufT * GN * B_;
    float v = fp[(2 * g2) * B_ + b0 + bb] + fp[(2 * g2 + 1) * B_ + b0 + bb];
    lds[OFF_PART + g2 * 17 + bb] = v;
    __syncthreads();
    if (tid < 16) {
      float f = bf0 + wf0 * x[(b0 + tid) * T_ + (T_ - 1)];
      #pragma unroll
      for (int g2_ = 0; g2_ < 16; ++g2_) f += lds[OFF_PART + g2_ * 17 + tid];
      lds[OFF_F + tid] = f;
    }
    __syncthreads();
    int b = tid >> 4, i = tid & 15;
    float cf = AC[bufT * B_ * N_ + (b0 + b) * N_ + j0 + i]
             + lds[OFF_F + b] * Bst[(T_ - 1) * N_ + j0 + i];
    out[(long)B_ * T_ * N_ + (b0 + b) * N_ + j0 + i] = cf;
  }
}

extern "C" void kernel_launch(void* const* d_in, const int* in_sizes, int n_in,
                              void* d_out, int out_size, void* d_ws, size_t ws_size,
                              hipStream_t stream) {
  const float* x   = (const float*)d_in[0];
  const float* h0  = (const float*)d_in[1];
  const float* c0  = (const float*)d_in[2];
  const float* Wi  = (const float*)d_in[3];
  const float* bi  = (const float*)d_in[4];
  const float* Wh  = (const float*)d_in[5];
  const float* bh  = (const float*)d_in[6];
  const float* Wf  = (const float*)d_in[7];
  const float* bfp = (const float*)d_in[8];
  const float* Ast = (const float*)d_in[9];
  const float* Bst = (const float*)d_in[10];
  float* out = (float*)d_out;
  float* AC  = (float*)d_ws;                 // 2 x B x N ping-pong
  float* Fp  = AC + 2 * B_ * N_;             // 2 x GN x B f partials
  unsigned* bar = (unsigned*)(Fp + 2 * GN * B_);  // 8 group counters, 256B apart

  hipFuncSetAttribute(reinterpret_cast<const void*>(hippo_kernel),
                      hipFuncAttributeMaxDynamicSharedMemorySize,
                      SMEM_FLOATS * (int)sizeof(float));

  void* args[] = { &x, &h0, &c0, &Wi, &bi, &Wh, &bh, &Wf, &bfp, &Ast, &Bst,
                   &out, &AC, &Fp, &bar };
  hipLaunchCooperativeKernel(reinterpret_cast<const void*>(hippo_kernel),
                             dim3(WGS), dim3(THREADS), args,
                             SMEM_FLOATS * (unsigned)sizeof(float), stream);
}